// Round 6
// baseline (632.196 us; speedup 1.0000x reference)
//
#include <hip/hip_runtime.h>
#include <math.h>

// ---------------------------------------------------------------------------
// CrossAttentionGNNConv: N=50000, E=800000, D=64
// Two dispatches total:
//  1) fused_pre (512 blocks, persistent, grid barriers): MFMA projections +
//     CSR build (zero, rank-histogram, scan, atomic-free scatter).
//  2) node_attn: per-wave node attention with LDS-cached V rows.
// Layouts: qab[n][128] f32 = [q_a|q_b]; kab[n][128] bf16 = [k_a|k_b];
//          vtx[n][128] bf16 = [v_t|v_x]
// ---------------------------------------------------------------------------

#define D 64
#define CAP 96
#define PC 24
#define NINF -3.0e38f
#define GRID_PRE 512
#define MAGIC 0x4D416743
#define AROW 72
typedef unsigned short ushortT;
typedef unsigned long long ull;
typedef __attribute__((ext_vector_type(8))) short bf16x8;
typedef __attribute__((ext_vector_type(4))) float f32x4;

__device__ __forceinline__ float b2f(ushortT h) {
  return __uint_as_float(((unsigned)h) << 16);
}
__device__ __forceinline__ float b2f_lo(unsigned u) {
  return __uint_as_float(u << 16);
}
__device__ __forceinline__ float b2f_hi(unsigned u) {
  return __uint_as_float(u & 0xffff0000u);
}
__device__ __forceinline__ ushortT f2b(float f) {
  unsigned u = __float_as_uint(f);
  u += 0x7fffu + ((u >> 16) & 1u);
  return (ushortT)(u >> 16);
}

__device__ __forceinline__ bool wave_is64(const ull* __restrict__ ei, ull nNodes) {
  ull v = ei[threadIdx.x & 63];
  return __ballot(v >= nNodes) == 0ull;
}

// generation grid barrier; bar[0]=init flag, bar[1]=cnt, bar[2]=gen
__device__ __forceinline__ void gbar(int* cnt, int* gen) {
  __syncthreads();
  if (threadIdx.x == 0) {
    int g = __hip_atomic_load(gen, __ATOMIC_RELAXED, __HIP_MEMORY_SCOPE_AGENT);
    __threadfence();
    int prev = __hip_atomic_fetch_add(cnt, 1, __ATOMIC_ACQ_REL,
                                      __HIP_MEMORY_SCOPE_AGENT);
    if (prev == GRID_PRE - 1) {
      __hip_atomic_store(cnt, 0, __ATOMIC_RELAXED, __HIP_MEMORY_SCOPE_AGENT);
      __threadfence();
      __hip_atomic_fetch_add(gen, 1, __ATOMIC_ACQ_REL, __HIP_MEMORY_SCOPE_AGENT);
    } else {
      while (__hip_atomic_load(gen, __ATOMIC_ACQUIRE,
                               __HIP_MEMORY_SCOPE_AGENT) == g)
        __builtin_amdgcn_s_sleep(2);
    }
    __threadfence();
  }
  __syncthreads();
}

// ---------------------------------------------------------------------------
__global__ __launch_bounds__(256, 3) void fused_pre(
    const float* __restrict__ t_tgt, const float* __restrict__ x_tgt,
    const float* __restrict__ t_src, const float* __restrict__ x_src,
    const float* __restrict__ QaW, const float* __restrict__ Qab_,
    const float* __restrict__ QbW, const float* __restrict__ Qbb,
    const float* __restrict__ KaW, const float* __restrict__ Kab_,
    const float* __restrict__ Wt,
    const float* __restrict__ KbW, const float* __restrict__ Kbb,
    const float* __restrict__ Wx,
    float* __restrict__ qab, ushortT* __restrict__ kab, ushortT* __restrict__ vtx,
    const void* __restrict__ ei, int E, int N, int bpj,
    int* __restrict__ deg, int* __restrict__ rank, int* __restrict__ offs,
    int* __restrict__ ecol, int* __restrict__ bsum, int* __restrict__ bar) {
  __shared__ ushortT As[128 * AROW];
  __shared__ ushortT W0s[64 * AROW];
  __shared__ ushortT W1s[64 * AROW];
  const int tid = threadIdx.x;

  // ===================== Phase P: projection tiles =========================
  const int nTiles = 4 * bpj;
  for (int tile = blockIdx.x; tile < nTiles; tile += GRID_PRE) {
    __syncthreads();  // protect LDS across tile iterations
    const int job = tile / bpj;
    const int jb = tile % bpj;
    const float *X, *W0, *B0, *W1 = nullptr;
    switch (job) {
      case 0: X = t_tgt; W0 = QaW; B0 = Qab_; break;
      case 1: X = x_tgt; W0 = QbW; B0 = Qbb; break;
      case 2: X = t_src; W0 = KaW; B0 = Kab_; W1 = Wt; break;
      default: X = x_src; W0 = KbW; B0 = Kbb; W1 = Wx; break;
    }
    const bool dual = (job >= 2);
    const int half = (job & 1) ? 64 : 0;
    const int base = jb * 128;

#pragma unroll
    for (int r = 0; r < 8; ++r) {
      int idx = tid + 256 * r;
      int row = idx >> 4, k4 = idx & 15;
      int gnode = base + row;
      float4 v = make_float4(0.f, 0.f, 0.f, 0.f);
      if (gnode < N) v = *(const float4*)(X + (size_t)gnode * D + k4 * 4);
      ushort4 h;
      h.x = f2b(v.x); h.y = f2b(v.y); h.z = f2b(v.z); h.w = f2b(v.w);
      *(ushort4*)&As[row * AROW + k4 * 4] = h;
    }
#pragma unroll
    for (int r = 0; r < 4; ++r) {
      int idx = tid + 256 * r;
      int row = idx >> 4, k4 = idx & 15;
      float4 v = *(const float4*)(W0 + row * D + k4 * 4);
      ushort4 h;
      h.x = f2b(v.x); h.y = f2b(v.y); h.z = f2b(v.z); h.w = f2b(v.w);
      *(ushort4*)&W0s[row * AROW + k4 * 4] = h;
    }
    if (dual) {
#pragma unroll
      for (int r = 0; r < 4; ++r) {
        int idx = tid + 256 * r;
        int row = idx >> 4, k4 = idx & 15;
        float4 v = *(const float4*)(W1 + row * D + k4 * 4);
        ushort4 h;
        h.x = f2b(v.x); h.y = f2b(v.y); h.z = f2b(v.z); h.w = f2b(v.w);
        *(ushort4*)&W1s[row * AROW + k4 * 4] = h;
      }
    }
    __syncthreads();

    const int lane = tid & 63;
    const int wid = tid >> 6;
    const int m16 = lane & 15;
    const int quad = lane >> 4;

    f32x4 acc0[2][4], acc1[2][4];
#pragma unroll
    for (int mt = 0; mt < 2; ++mt)
#pragma unroll
      for (int nt = 0; nt < 4; ++nt) {
        acc0[mt][nt] = (f32x4){0.f, 0.f, 0.f, 0.f};
        acc1[mt][nt] = (f32x4){0.f, 0.f, 0.f, 0.f};
      }
#pragma unroll
    for (int ko = 0; ko < 2; ++ko) {
      const int koff = ko * 32 + quad * 8;
      bf16x8 a[2];
#pragma unroll
      for (int mt = 0; mt < 2; ++mt)
        a[mt] = *(const bf16x8*)&As[(wid * 32 + mt * 16 + m16) * AROW + koff];
#pragma unroll
      for (int nt = 0; nt < 4; ++nt) {
        bf16x8 b = *(const bf16x8*)&W0s[(nt * 16 + m16) * AROW + koff];
#pragma unroll
        for (int mt = 0; mt < 2; ++mt)
          acc0[mt][nt] = __builtin_amdgcn_mfma_f32_16x16x32_bf16(
              a[mt], b, acc0[mt][nt], 0, 0, 0);
      }
      if (dual) {
#pragma unroll
        for (int nt = 0; nt < 4; ++nt) {
          bf16x8 b = *(const bf16x8*)&W1s[(nt * 16 + m16) * AROW + koff];
#pragma unroll
          for (int mt = 0; mt < 2; ++mt)
            acc1[mt][nt] = __builtin_amdgcn_mfma_f32_16x16x32_bf16(
                a[mt], b, acc1[mt][nt], 0, 0, 0);
        }
      }
    }

    float bias[4];
#pragma unroll
    for (int nt = 0; nt < 4; ++nt) bias[nt] = B0[nt * 16 + m16];
#pragma unroll
    for (int mt = 0; mt < 2; ++mt) {
#pragma unroll
      for (int reg = 0; reg < 4; ++reg) {
        int node = base + wid * 32 + mt * 16 + quad * 4 + reg;
        if (node < N) {
          if (!dual) {
            float* dst = qab + (size_t)node * 128 + half;
#pragma unroll
            for (int nt = 0; nt < 4; ++nt)
              dst[nt * 16 + m16] = acc0[mt][nt][reg] + bias[nt];
          } else {
            ushortT* dk = kab + (size_t)node * 128 + half;
            ushortT* dv = vtx + (size_t)node * 128 + half;
#pragma unroll
            for (int nt = 0; nt < 4; ++nt) {
              dk[nt * 16 + m16] = f2b(acc0[mt][nt][reg] + bias[nt]);
              dv[nt * 16 + m16] = f2b(acc1[mt][nt][reg]);
            }
          }
        }
      }
    }
  }

  // ===================== barrier init handshake ============================
  if (blockIdx.x == 0 && tid == 0) {
    bar[1] = 0;
    bar[2] = 0;
    __threadfence();
    __hip_atomic_store(&bar[0], MAGIC, __ATOMIC_RELEASE, __HIP_MEMORY_SCOPE_AGENT);
  }
  if (tid == 0) {
    while (__hip_atomic_load(&bar[0], __ATOMIC_ACQUIRE,
                             __HIP_MEMORY_SCOPE_AGENT) != MAGIC)
      __builtin_amdgcn_s_sleep(2);
  }
  __syncthreads();

  const int gtid = blockIdx.x * 256 + tid;
  int* sI = (int*)As;  // alias LDS for scan phases

  // ===================== Phase 0: zero degrees =============================
  for (int i = gtid; i < N; i += GRID_PRE * 256) deg[i] = 0;
  gbar(&bar[1], &bar[2]);

  // ===================== Phase 1: rank histogram ===========================
  {
    const bool is64 = wave_is64((const ull*)ei, (ull)N);
    const int stride4 = GRID_PRE * 256 * 4;
    for (int i4 = gtid * 4; i4 < E; i4 += stride4) {
      int m = E - i4; if (m > 4) m = 4;
      if (is64) {
        const long long* p = (const long long*)ei;
        for (int j = 0; j < m; ++j) {
          int r = (int)p[i4 + j];
          rank[i4 + j] = atomicAdd(&deg[r], 1);
        }
      } else {
        const int* p = (const int*)ei;
        for (int j = 0; j < m; ++j) {
          int r = p[i4 + j];
          rank[i4 + j] = atomicAdd(&deg[r], 1);
        }
      }
    }
  }
  gbar(&bar[1], &bar[2]);

  // ===================== Phase 2: per-block degree sums ====================
  {
    int n = gtid;
    int d = (n < N) ? deg[n] : 0;
    sI[tid] = d;
    __syncthreads();
    for (int s = 128; s > 0; s >>= 1) {
      if (tid < s) sI[tid] += sI[tid + s];
      __syncthreads();
    }
    if (tid == 0) bsum[blockIdx.x] = sI[0];
  }
  gbar(&bar[1], &bar[2]);

  // ===================== Phase 3: block 0 scans bsum[0..255] ===============
  // (blocks >= 196 hold no nodes; their sums are zero)
  if (blockIdx.x == 0) {
    int v = bsum[tid];
    sI[tid] = v;
    __syncthreads();
    for (int off = 1; off < 256; off <<= 1) {
      int add = (tid >= off) ? sI[tid - off] : 0;
      __syncthreads();
      sI[tid] += add;
      __syncthreads();
    }
    bsum[tid] = sI[tid] - v;  // exclusive
  }
  gbar(&bar[1], &bar[2]);

  // ===================== Phase 4: node offsets =============================
  {
    int n = gtid;
    int d = (n < N) ? deg[n] : 0;
    sI[tid] = d;
    __syncthreads();
    for (int off = 1; off < 256; off <<= 1) {
      int add = (tid >= off) ? sI[tid - off] : 0;
      __syncthreads();
      sI[tid] += add;
      __syncthreads();
    }
    if (blockIdx.x < 256 && n <= N) {
      int excl = sI[tid] - d + bsum[blockIdx.x];
      offs[n] = excl;
    }
  }
  gbar(&bar[1], &bar[2]);

  // ===================== Phase 5: atomic-free scatter ======================
  {
    const bool is64 = wave_is64((const ull*)ei, (ull)N);
    const int stride4 = GRID_PRE * 256 * 4;
    for (int i4 = gtid * 4; i4 < E; i4 += stride4) {
      int m = E - i4; if (m > 4) m = 4;
      if (is64) {
        const long long* p = (const long long*)ei;
        for (int j = 0; j < m; ++j) {
          int r = (int)p[i4 + j];
          int c = (int)p[(long long)E + i4 + j];
          ecol[offs[r] + rank[i4 + j]] = c;
        }
      } else {
        const int* p = (const int*)ei;
        for (int j = 0; j < m; ++j) {
          int r = p[i4 + j];
          int c = p[E + i4 + j];
          ecol[offs[r] + rank[i4 + j]] = c;
        }
      }
    }
  }
}

// --- per-node attention + aggregation, one wave per destination node -------
__global__ __launch_bounds__(256) void node_attn(
    const float* __restrict__ qab, const ushortT* __restrict__ kab,
    const ushortT* __restrict__ vtx,
    const int* __restrict__ offs, const int* __restrict__ ecol,
    float* __restrict__ out_x, float* __restrict__ out_t, int nNodes) {
  __shared__ __align__(16) ushortT s_v[4][PC][136];  // cached V rows (272B pad)
  __shared__ float s_wa[4][CAP];
  __shared__ float s_wb[4][CAP];
  __shared__ int s_c[4][CAP];
  const int lane = threadIdx.x & 63;
  const int wid = threadIdx.x >> 6;
  const int sub = lane >> 4;   // edge within chunk of 4
  const int sl = lane & 15;    // sublane: 0-7 -> alpha dot, 8-15 -> beta dot
  const int gw = (blockIdx.x * blockDim.x + threadIdx.x) >> 6;
  const int nw = (gridDim.x * blockDim.x) >> 6;
  const float scale = 0.125f;

  for (int n = gw; n < nNodes; n += nw) {
    const int s = offs[n], e = offs[n + 1], deg = e - s;
    const size_t nb = (size_t)n * D;
    if (deg == 0) {
      out_x[nb + lane] = 0.f;
      out_t[nb + lane] = 0.f;
      continue;
    }
    float acc_t = 0.f, acc_x = 0.f;
    if (deg <= CAP) {
      const float4 q0 = *(const float4*)(qab + (size_t)n * 128 + sl * 8);
      const float4 q1 = *(const float4*)(qab + (size_t)n * 128 + sl * 8 + 4);
      // Phase A: scores (4 edges/pass, both dots at once) + V-row prefetch
      for (int i = 0; i < deg; i += 4) {
        const int idx = i + sub;
        const bool act = idx < deg;
        const int c = ecol[s + (act ? idx : 0)];
        const uint4 u = *(const uint4*)(kab + (size_t)c * 128 + sl * 8);
        uint4 w = make_uint4(0, 0, 0, 0);
        if (idx < PC) w = *(const uint4*)(vtx + (size_t)c * 128 + sl * 8);
        float v = q0.x * b2f_lo(u.x);
        v = fmaf(q0.y, b2f_hi(u.x), v);
        v = fmaf(q0.z, b2f_lo(u.y), v);
        v = fmaf(q0.w, b2f_hi(u.y), v);
        v = fmaf(q1.x, b2f_lo(u.z), v);
        v = fmaf(q1.y, b2f_hi(u.z), v);
        v = fmaf(q1.z, b2f_lo(u.w), v);
        v = fmaf(q1.w, b2f_hi(u.w), v);
#pragma unroll
        for (int off = 1; off < 8; off <<= 1) v += __shfl_xor(v, off);
        if (act && idx < PC) *(uint4*)&s_v[wid][idx][sl * 8] = w;
        if (act) {
          if (sl == 0) { s_wa[wid][idx] = v * scale; s_c[wid][idx] = c; }
          if (sl == 8) s_wb[wid][idx] = v * scale;
        }
      }
      // Phase B: parallel softmax
      float sa = (lane < deg) ? s_wa[wid][lane] : NINF;
      float sb = (lane < deg) ? s_wb[wid][lane] : NINF;
      if (deg <= 64) {
        float ma = sa, mb = sb;
#pragma unroll
        for (int off = 1; off < 64; off <<= 1) {
          ma = fmaxf(ma, __shfl_xor(ma, off));
          mb = fmaxf(mb, __shfl_xor(mb, off));
        }
        float ea = __expf(sa - ma), eb = __expf(sb - mb);
        float da = ea, db = eb;
#pragma unroll
        for (int off = 1; off < 64; off <<= 1) {
          da += __shfl_xor(da, off);
          db += __shfl_xor(db, off);
        }
        const float ia = 1.0f / da, ib = 1.0f / db;
        if (lane < deg) { s_wa[wid][lane] = ea * ia; s_wb[wid][lane] = eb * ib; }
      } else {
        float sa1 = (lane + 64 < deg) ? s_wa[wid][lane + 64] : NINF;
        float sb1 = (lane + 64 < deg) ? s_wb[wid][lane + 64] : NINF;
        float ma = fmaxf(sa, sa1), mb = fmaxf(sb, sb1);
#pragma unroll
        for (int off = 1; off < 64; off <<= 1) {
          ma = fmaxf(ma, __shfl_xor(ma, off));
          mb = fmaxf(mb, __shfl_xor(mb, off));
        }
        float ea0 = __expf(sa - ma), ea1 = __expf(sa1 - ma);
        float eb0 = __expf(sb - mb), eb1 = __expf(sb1 - mb);
        float da = ea0 + ea1, db = eb0 + eb1;
#pragma unroll
        for (int off = 1; off < 64; off <<= 1) {
          da += __shfl_xor(da, off);
          db += __shfl_xor(db, off);
        }
        const float ia = 1.0f / da, ib = 1.0f / db;
        if (lane < deg) { s_wa[wid][lane] = ea0 * ia; s_wb[wid][lane] = eb0 * ib; }
        if (lane + 64 < deg) {
          s_wa[wid][lane + 64] = ea1 * ia;
          s_wb[wid][lane + 64] = eb1 * ib;
        }
      }
      // Phase C: aggregation — LDS for cached edges, global for the tail
      const int lim = deg < PC ? deg : PC;
      int i = 0;
      for (; i + 2 <= lim; i += 2) {
        float t0 = b2f(s_v[wid][i][lane]);
        float x0 = b2f(s_v[wid][i][lane + 64]);
        float t1 = b2f(s_v[wid][i + 1][lane]);
        float x1 = b2f(s_v[wid][i + 1][lane + 64]);
        acc_t = fmaf(s_wa[wid][i], t0, acc_t);
        acc_t = fmaf(s_wa[wid][i + 1], t1, acc_t);
        acc_x = fmaf(s_wb[wid][i], x0, acc_x);
        acc_x = fmaf(s_wb[wid][i + 1], x1, acc_x);
      }
      for (; i < lim; ++i) {
        acc_t = fmaf(s_wa[wid][i], b2f(s_v[wid][i][lane]), acc_t);
        acc_x = fmaf(s_wb[wid][i], b2f(s_v[wid][i][lane + 64]), acc_x);
      }
      for (; i < deg; ++i) {
        const int c0 = s_c[wid][i];
        const ushortT* b0 = vtx + (size_t)c0 * 128;
        acc_t = fmaf(s_wa[wid][i], b2f(b0[lane]), acc_t);
        acc_x = fmaf(s_wb[wid][i], b2f(b0[lane + 64]), acc_x);
      }
    } else {
      // rare fallback: serial full-wave online softmax + recompute
      const float qla = qab[(size_t)n * 128 + lane];
      const float qlb = qab[(size_t)n * 128 + 64 + lane];
      float ma = NINF, mb = NINF, da = 0.f, db = 0.f;
      for (int i = s; i < e; ++i) {
        int c = ecol[i];
        float va = qla * b2f(kab[(size_t)c * 128 + lane]);
        float vb = qlb * b2f(kab[(size_t)c * 128 + 64 + lane]);
#pragma unroll
        for (int off = 1; off < 64; off <<= 1) {
          va += __shfl_xor(va, off);
          vb += __shfl_xor(vb, off);
        }
        va *= scale; vb *= scale;
        float na = fmaxf(ma, va);
        da = da * __expf(ma - na) + __expf(va - na);
        ma = na;
        float nb2 = fmaxf(mb, vb);
        db = db * __expf(mb - nb2) + __expf(vb - nb2);
        mb = nb2;
      }
      const float ia = 1.0f / da, ib = 1.0f / db;
      for (int i = s; i < e; ++i) {
        int c = ecol[i];
        float va = qla * b2f(kab[(size_t)c * 128 + lane]);
        float vb = qlb * b2f(kab[(size_t)c * 128 + 64 + lane]);
#pragma unroll
        for (int off = 1; off < 64; off <<= 1) {
          va += __shfl_xor(va, off);
          vb += __shfl_xor(vb, off);
        }
        float al = __expf(va * scale - ma) * ia;
        float be = __expf(vb * scale - mb) * ib;
        const ushortT* b0 = vtx + (size_t)c * 128;
        acc_t = fmaf(al, b2f(b0[lane]), acc_t);
        acc_x = fmaf(be, b2f(b0[lane + 64]), acc_x);
      }
    }
    out_t[nb + lane] = acc_t;
    out_x[nb + lane] = acc_x;
  }
}

// ---------------------------------------------------------------------------
extern "C" void kernel_launch(void* const* d_in, const int* in_sizes, int n_in,
                              void* d_out, int out_size, void* d_ws, size_t ws_size,
                              hipStream_t stream) {
  const float* x_src = (const float*)d_in[0];
  const float* x_tgt = (const float*)d_in[1];
  const float* t_src = (const float*)d_in[2];
  const float* t_tgt = (const float*)d_in[3];
  const void* edge_index = d_in[4];
  const float* W_x = (const float*)d_in[5];
  const float* W_t = (const float*)d_in[6];
  const float* Ka_W = (const float*)d_in[7];
  const float* Ka_b = (const float*)d_in[8];
  const float* Qa_W = (const float*)d_in[9];
  const float* Qa_b = (const float*)d_in[10];
  const float* Kb_W = (const float*)d_in[11];
  const float* Kb_b = (const float*)d_in[12];
  const float* Qb_W = (const float*)d_in[13];
  const float* Qb_b = (const float*)d_in[14];

  const int N = in_sizes[0] / D;
  const int E = in_sizes[4] / 2;

  char* ws = (char*)d_ws;
  size_t ofs = 0;
  auto carve = [&](size_t bytes) {
    size_t p = ofs;
    ofs += (bytes + 255) & ~(size_t)255;
    return p;
  };
  float* qab = (float*)(ws + carve((size_t)N * 128 * 4));
  ushortT* kab = (ushortT*)(ws + carve((size_t)N * 128 * 2));
  ushortT* vtx = (ushortT*)(ws + carve((size_t)N * 128 * 2));
  int* offs = (int*)(ws + carve(((size_t)N + 1) * 4));
  int* deg = (int*)(ws + carve((size_t)N * 4));
  int* rank = (int*)(ws + carve((size_t)E * 4));
  int* ecol = (int*)(ws + carve((size_t)E * 4));
  int* bsum = (int*)(ws + carve((size_t)GRID_PRE * 4));
  int* bar = (int*)(ws + carve(64));
  (void)ws_size;

  float* out_x = (float*)d_out;
  float* out_t = out_x + (size_t)N * D;

  const int bpj = (N + 127) / 128;

  fused_pre<<<GRID_PRE, 256, 0, stream>>>(
      t_tgt, x_tgt, t_src, x_src,
      Qa_W, Qa_b, Qb_W, Qb_b,
      Ka_W, Ka_b, W_t,
      Kb_W, Kb_b, W_x,
      qab, kab, vtx,
      edge_index, E, N, bpj,
      deg, rank, offs, ecol, bsum, bar);

  node_attn<<<(N + 3) / 4, 256, 0, stream>>>(qab, kab, vtx, offs, ecol,
                                             out_x, out_t, N);
}

// Round 7
// 333.452 us; speedup vs baseline: 1.8959x; 1.8959x over previous
//
#include <hip/hip_runtime.h>
#include <math.h>

// ---------------------------------------------------------------------------
// CrossAttentionGNNConv: N=50000, E=800000, D=64
// 5 dispatches: memset(deg) -> edge_rank -> scan_offs(1 block) ->
//               scat_proj (scatter || MFMA projections) -> node_attn
// Layouts: qab[n][128] f32 = [q_a|q_b]; kab[n][128] bf16 = [k_a|k_b];
//          vtx[n][128] bf16 = [v_t|v_x]
// NOTE (R6 lesson): persistent-kernel grid barriers on MI355X cost ~100x the
// model (cross-XCD coherence); kernel boundaries are cheaper. Never again.
// ---------------------------------------------------------------------------

#define D 64
#define CAP 96
#define PC 24
#define NINF -3.0e38f
#define AROW 72
typedef unsigned short ushortT;
typedef unsigned long long ull;
typedef __attribute__((ext_vector_type(8))) short bf16x8;
typedef __attribute__((ext_vector_type(4))) float f32x4;

__device__ __forceinline__ float b2f(ushortT h) {
  return __uint_as_float(((unsigned)h) << 16);
}
__device__ __forceinline__ float b2f_lo(unsigned u) {
  return __uint_as_float(u << 16);
}
__device__ __forceinline__ float b2f_hi(unsigned u) {
  return __uint_as_float(u & 0xffff0000u);
}
__device__ __forceinline__ ushortT f2b(float f) {
  unsigned u = __float_as_uint(f);
  u += 0x7fffu + ((u >> 16) & 1u);
  return (ushortT)(u >> 16);
}

__device__ __forceinline__ bool wave_is64(const ull* __restrict__ ei, ull nNodes) {
  ull v = ei[threadIdx.x & 63];
  return __ballot(v >= nNodes) == 0ull;
}

// --- CSR pass 1: histogram rows, record per-edge rank ----------------------
__global__ void edge_rank(const void* __restrict__ ei, int* __restrict__ deg,
                          int* __restrict__ rank, int E, ull nNodes) {
  const bool is64 = wave_is64((const ull*)ei, nNodes);
  int base = (blockIdx.x * blockDim.x + threadIdx.x) << 2;
  if (base >= E) return;
  int m = E - base; if (m > 4) m = 4;
  if (is64) {
    const long long* p = (const long long*)ei;
    for (int j = 0; j < m; ++j) {
      int r = (int)p[base + j];
      rank[base + j] = atomicAdd(&deg[r], 1);
    }
  } else {
    const int* p = (const int*)ei;
    for (int j = 0; j < m; ++j) {
      int r = p[base + j];
      rank[base + j] = atomicAdd(&deg[r], 1);
    }
  }
}

// --- CSR pass 2: single-block exclusive scan deg -> offs -------------------
__global__ __launch_bounds__(1024) void scan_offs(const int* __restrict__ deg,
                                                  int* __restrict__ offs,
                                                  int N, int E) {
  __shared__ int wsum[16];
  __shared__ int carryS;
  const int tid = threadIdx.x;
  const int lane = tid & 63, wv = tid >> 6;
  if (tid == 0) carryS = 0;
  __syncthreads();
  int d_next = (tid < N) ? deg[tid] : 0;  // prefetch tile 0
  for (int base = 0; base < N; base += 1024) {
    const int idx = base + tid;
    const int d = d_next;
    const int nidx = base + 1024 + tid;
    d_next = (nidx < N) ? deg[nidx] : 0;  // prefetch next tile (hides latency)
    // inclusive scan within wave
    int x = d;
#pragma unroll
    for (int off = 1; off < 64; off <<= 1) {
      int y = __shfl_up(x, off);
      if (lane >= off) x += y;
    }
    if (lane == 63) wsum[wv] = x;
    __syncthreads();
    if (wv == 0) {
      int s = (lane < 16) ? wsum[lane] : 0;
#pragma unroll
      for (int off = 1; off < 16; off <<= 1) {
        int y = __shfl_up(s, off);
        if (lane >= off) s += y;
      }
      if (lane < 16) wsum[lane] = s;
    }
    __syncthreads();
    const int waveOff = (wv > 0) ? wsum[wv - 1] : 0;
    const int excl = x - d + waveOff + carryS;
    if (idx < N) offs[idx] = excl;
    __syncthreads();  // all reads of carryS/wsum done
    if (tid == 0) carryS += wsum[15];
    __syncthreads();  // carryS updated before next tile
  }
  if (tid == 0) offs[N] = E;
}

// --- fused: atomic-free scatter (blocks < scatBlocks) || MFMA proj ---------
__global__ __launch_bounds__(256) void scat_proj(
    const void* __restrict__ ei, const int* __restrict__ offs,
    const int* __restrict__ rank, int* __restrict__ ecol, int E,
    const float* __restrict__ t_tgt, const float* __restrict__ x_tgt,
    const float* __restrict__ t_src, const float* __restrict__ x_src,
    const float* __restrict__ QaW, const float* __restrict__ Qab_,
    const float* __restrict__ QbW, const float* __restrict__ Qbb,
    const float* __restrict__ KaW, const float* __restrict__ Kab_,
    const float* __restrict__ Wt,
    const float* __restrict__ KbW, const float* __restrict__ Kbb,
    const float* __restrict__ Wx,
    float* __restrict__ qab, ushortT* __restrict__ kab, ushortT* __restrict__ vtx,
    int N, int bpj, int scatBlocks) {
  __shared__ ushortT As[128 * AROW];
  __shared__ ushortT W0s[64 * AROW];
  __shared__ ushortT W1s[64 * AROW];
  const int tid = threadIdx.x;

  if (blockIdx.x < scatBlocks) {
    // ---------------- scatter: ecol[offs[r] + rank[e]] = c ----------------
    const bool is64 = wave_is64((const ull*)ei, (ull)N);
    int base = (blockIdx.x * 256 + tid) << 2;
    if (base >= E) return;
    int m = E - base; if (m > 4) m = 4;
    if (is64) {
      const long long* p = (const long long*)ei;
      for (int j = 0; j < m; ++j) {
        int r = (int)p[base + j];
        int c = (int)p[(long long)E + base + j];
        ecol[offs[r] + rank[base + j]] = c;
      }
    } else {
      const int* p = (const int*)ei;
      for (int j = 0; j < m; ++j) {
        int r = p[base + j];
        int c = p[E + base + j];
        ecol[offs[r] + rank[base + j]] = c;
      }
    }
    return;
  }

  // ---------------- projection tile ----------------
  const int tile = blockIdx.x - scatBlocks;
  const int job = tile / bpj;
  const int jb = tile % bpj;
  const float *X, *W0, *B0, *W1 = nullptr;
  switch (job) {
    case 0: X = t_tgt; W0 = QaW; B0 = Qab_; break;
    case 1: X = x_tgt; W0 = QbW; B0 = Qbb; break;
    case 2: X = t_src; W0 = KaW; B0 = Kab_; W1 = Wt; break;
    default: X = x_src; W0 = KbW; B0 = Kbb; W1 = Wx; break;
  }
  const bool dual = (job >= 2);
  const int half = (job & 1) ? 64 : 0;
  const int base = jb * 128;

#pragma unroll
  for (int r = 0; r < 8; ++r) {
    int idx = tid + 256 * r;
    int row = idx >> 4, k4 = idx & 15;
    int gnode = base + row;
    float4 v = make_float4(0.f, 0.f, 0.f, 0.f);
    if (gnode < N) v = *(const float4*)(X + (size_t)gnode * D + k4 * 4);
    ushort4 h;
    h.x = f2b(v.x); h.y = f2b(v.y); h.z = f2b(v.z); h.w = f2b(v.w);
    *(ushort4*)&As[row * AROW + k4 * 4] = h;
  }
#pragma unroll
  for (int r = 0; r < 4; ++r) {
    int idx = tid + 256 * r;
    int row = idx >> 4, k4 = idx & 15;
    float4 v = *(const float4*)(W0 + row * D + k4 * 4);
    ushort4 h;
    h.x = f2b(v.x); h.y = f2b(v.y); h.z = f2b(v.z); h.w = f2b(v.w);
    *(ushort4*)&W0s[row * AROW + k4 * 4] = h;
  }
  if (dual) {
#pragma unroll
    for (int r = 0; r < 4; ++r) {
      int idx = tid + 256 * r;
      int row = idx >> 4, k4 = idx & 15;
      float4 v = *(const float4*)(W1 + row * D + k4 * 4);
      ushort4 h;
      h.x = f2b(v.x); h.y = f2b(v.y); h.z = f2b(v.z); h.w = f2b(v.w);
      *(ushort4*)&W1s[row * AROW + k4 * 4] = h;
    }
  }
  __syncthreads();

  const int lane = tid & 63;
  const int wid = tid >> 6;
  const int m16 = lane & 15;
  const int quad = lane >> 4;

  f32x4 acc0[2][4], acc1[2][4];
#pragma unroll
  for (int mt = 0; mt < 2; ++mt)
#pragma unroll
    for (int nt = 0; nt < 4; ++nt) {
      acc0[mt][nt] = (f32x4){0.f, 0.f, 0.f, 0.f};
      acc1[mt][nt] = (f32x4){0.f, 0.f, 0.f, 0.f};
    }
#pragma unroll
  for (int ko = 0; ko < 2; ++ko) {
    const int koff = ko * 32 + quad * 8;
    bf16x8 a[2];
#pragma unroll
    for (int mt = 0; mt < 2; ++mt)
      a[mt] = *(const bf16x8*)&As[(wid * 32 + mt * 16 + m16) * AROW + koff];
#pragma unroll
    for (int nt = 0; nt < 4; ++nt) {
      bf16x8 b = *(const bf16x8*)&W0s[(nt * 16 + m16) * AROW + koff];
#pragma unroll
      for (int mt = 0; mt < 2; ++mt)
        acc0[mt][nt] = __builtin_amdgcn_mfma_f32_16x16x32_bf16(
            a[mt], b, acc0[mt][nt], 0, 0, 0);
    }
    if (dual) {
#pragma unroll
      for (int nt = 0; nt < 4; ++nt) {
        bf16x8 b = *(const bf16x8*)&W1s[(nt * 16 + m16) * AROW + koff];
#pragma unroll
        for (int mt = 0; mt < 2; ++mt)
          acc1[mt][nt] = __builtin_amdgcn_mfma_f32_16x16x32_bf16(
              a[mt], b, acc1[mt][nt], 0, 0, 0);
      }
    }
  }

  float bias[4];
#pragma unroll
  for (int nt = 0; nt < 4; ++nt) bias[nt] = B0[nt * 16 + m16];
#pragma unroll
  for (int mt = 0; mt < 2; ++mt) {
#pragma unroll
    for (int reg = 0; reg < 4; ++reg) {
      int node = base + wid * 32 + mt * 16 + quad * 4 + reg;
      if (node < N) {
        if (!dual) {
          float* dst = qab + (size_t)node * 128 + half;
#pragma unroll
          for (int nt = 0; nt < 4; ++nt)
            dst[nt * 16 + m16] = acc0[mt][nt][reg] + bias[nt];
        } else {
          ushortT* dk = kab + (size_t)node * 128 + half;
          ushortT* dv = vtx + (size_t)node * 128 + half;
#pragma unroll
          for (int nt = 0; nt < 4; ++nt) {
            dk[nt * 16 + m16] = f2b(acc0[mt][nt][reg] + bias[nt]);
            dv[nt * 16 + m16] = f2b(acc1[mt][nt][reg]);
          }
        }
      }
    }
  }
}

// --- per-node attention + aggregation, one wave per destination node -------
__global__ __launch_bounds__(256) void node_attn(
    const float* __restrict__ qab, const ushortT* __restrict__ kab,
    const ushortT* __restrict__ vtx,
    const int* __restrict__ offs, const int* __restrict__ ecol,
    float* __restrict__ out_x, float* __restrict__ out_t, int nNodes) {
  __shared__ __align__(16) ushortT s_v[4][PC][136];  // cached V rows
  __shared__ float s_wa[4][CAP];
  __shared__ float s_wb[4][CAP];
  __shared__ int s_c[4][CAP];
  const int lane = threadIdx.x & 63;
  const int wid = threadIdx.x >> 6;
  const int sub = lane >> 4;   // edge within chunk of 4
  const int sl = lane & 15;    // sublane: 0-7 -> alpha dot, 8-15 -> beta dot
  const int gw = (blockIdx.x * blockDim.x + threadIdx.x) >> 6;
  const int nw = (gridDim.x * blockDim.x) >> 6;
  const float scale = 0.125f;

  for (int n = gw; n < nNodes; n += nw) {
    const int s = offs[n], e = offs[n + 1], deg = e - s;
    const size_t nb = (size_t)n * D;
    if (deg == 0) {
      out_x[nb + lane] = 0.f;
      out_t[nb + lane] = 0.f;
      continue;
    }
    float acc_t = 0.f, acc_x = 0.f;
    if (deg <= CAP) {
      const float4 q0 = *(const float4*)(qab + (size_t)n * 128 + sl * 8);
      const float4 q1 = *(const float4*)(qab + (size_t)n * 128 + sl * 8 + 4);
      // Phase A: scores (4 edges/pass, both dots at once) + V-row prefetch
      for (int i = 0; i < deg; i += 4) {
        const int idx = i + sub;
        const bool act = idx < deg;
        const int c = ecol[s + (act ? idx : 0)];
        const uint4 u = *(const uint4*)(kab + (size_t)c * 128 + sl * 8);
        uint4 w = make_uint4(0, 0, 0, 0);
        if (idx < PC) w = *(const uint4*)(vtx + (size_t)c * 128 + sl * 8);
        float v = q0.x * b2f_lo(u.x);
        v = fmaf(q0.y, b2f_hi(u.x), v);
        v = fmaf(q0.z, b2f_lo(u.y), v);
        v = fmaf(q0.w, b2f_hi(u.y), v);
        v = fmaf(q1.x, b2f_lo(u.z), v);
        v = fmaf(q1.y, b2f_hi(u.z), v);
        v = fmaf(q1.z, b2f_lo(u.w), v);
        v = fmaf(q1.w, b2f_hi(u.w), v);
#pragma unroll
        for (int off = 1; off < 8; off <<= 1) v += __shfl_xor(v, off);
        if (act && idx < PC) *(uint4*)&s_v[wid][idx][sl * 8] = w;
        if (act) {
          if (sl == 0) { s_wa[wid][idx] = v * scale; s_c[wid][idx] = c; }
          if (sl == 8) s_wb[wid][idx] = v * scale;
        }
      }
      // Phase B: parallel softmax
      float sa = (lane < deg) ? s_wa[wid][lane] : NINF;
      float sb = (lane < deg) ? s_wb[wid][lane] : NINF;
      if (deg <= 64) {
        float ma = sa, mb = sb;
#pragma unroll
        for (int off = 1; off < 64; off <<= 1) {
          ma = fmaxf(ma, __shfl_xor(ma, off));
          mb = fmaxf(mb, __shfl_xor(mb, off));
        }
        float ea = __expf(sa - ma), eb = __expf(sb - mb);
        float da = ea, db = eb;
#pragma unroll
        for (int off = 1; off < 64; off <<= 1) {
          da += __shfl_xor(da, off);
          db += __shfl_xor(db, off);
        }
        const float ia = 1.0f / da, ib = 1.0f / db;
        if (lane < deg) { s_wa[wid][lane] = ea * ia; s_wb[wid][lane] = eb * ib; }
      } else {
        float sa1 = (lane + 64 < deg) ? s_wa[wid][lane + 64] : NINF;
        float sb1 = (lane + 64 < deg) ? s_wb[wid][lane + 64] : NINF;
        float ma = fmaxf(sa, sa1), mb = fmaxf(sb, sb1);
#pragma unroll
        for (int off = 1; off < 64; off <<= 1) {
          ma = fmaxf(ma, __shfl_xor(ma, off));
          mb = fmaxf(mb, __shfl_xor(mb, off));
        }
        float ea0 = __expf(sa - ma), ea1 = __expf(sa1 - ma);
        float eb0 = __expf(sb - mb), eb1 = __expf(sb1 - mb);
        float da = ea0 + ea1, db = eb0 + eb1;
#pragma unroll
        for (int off = 1; off < 64; off <<= 1) {
          da += __shfl_xor(da, off);
          db += __shfl_xor(db, off);
        }
        const float ia = 1.0f / da, ib = 1.0f / db;
        if (lane < deg) { s_wa[wid][lane] = ea0 * ia; s_wb[wid][lane] = eb0 * ib; }
        if (lane + 64 < deg) {
          s_wa[wid][lane + 64] = ea1 * ia;
          s_wb[wid][lane + 64] = eb1 * ib;
        }
      }
      // Phase C: aggregation — LDS for cached edges, global for the tail
      const int lim = deg < PC ? deg : PC;
      int i = 0;
      for (; i + 2 <= lim; i += 2) {
        float t0 = b2f(s_v[wid][i][lane]);
        float x0 = b2f(s_v[wid][i][lane + 64]);
        float t1 = b2f(s_v[wid][i + 1][lane]);
        float x1 = b2f(s_v[wid][i + 1][lane + 64]);
        acc_t = fmaf(s_wa[wid][i], t0, acc_t);
        acc_t = fmaf(s_wa[wid][i + 1], t1, acc_t);
        acc_x = fmaf(s_wb[wid][i], x0, acc_x);
        acc_x = fmaf(s_wb[wid][i + 1], x1, acc_x);
      }
      for (; i < lim; ++i) {
        acc_t = fmaf(s_wa[wid][i], b2f(s_v[wid][i][lane]), acc_t);
        acc_x = fmaf(s_wb[wid][i], b2f(s_v[wid][i][lane + 64]), acc_x);
      }
      for (; i < deg; ++i) {
        const int c0 = s_c[wid][i];
        const ushortT* b0 = vtx + (size_t)c0 * 128;
        acc_t = fmaf(s_wa[wid][i], b2f(b0[lane]), acc_t);
        acc_x = fmaf(s_wb[wid][i], b2f(b0[lane + 64]), acc_x);
      }
    } else {
      // rare fallback: serial full-wave online softmax + recompute
      const float qla = qab[(size_t)n * 128 + lane];
      const float qlb = qab[(size_t)n * 128 + 64 + lane];
      float ma = NINF, mb = NINF, da = 0.f, db = 0.f;
      for (int i = s; i < e; ++i) {
        int c = ecol[i];
        float va = qla * b2f(kab[(size_t)c * 128 + lane]);
        float vb = qlb * b2f(kab[(size_t)c * 128 + 64 + lane]);
#pragma unroll
        for (int off = 1; off < 64; off <<= 1) {
          va += __shfl_xor(va, off);
          vb += __shfl_xor(vb, off);
        }
        va *= scale; vb *= scale;
        float na = fmaxf(ma, va);
        da = da * __expf(ma - na) + __expf(va - na);
        ma = na;
        float nb2 = fmaxf(mb, vb);
        db = db * __expf(mb - nb2) + __expf(vb - nb2);
        mb = nb2;
      }
      const float ia = 1.0f / da, ib = 1.0f / db;
      for (int i = s; i < e; ++i) {
        int c = ecol[i];
        float va = qla * b2f(kab[(size_t)c * 128 + lane]);
        float vb = qlb * b2f(kab[(size_t)c * 128 + 64 + lane]);
#pragma unroll
        for (int off = 1; off < 64; off <<= 1) {
          va += __shfl_xor(va, off);
          vb += __shfl_xor(vb, off);
        }
        float al = __expf(va * scale - ma) * ia;
        float be = __expf(vb * scale - mb) * ib;
        const ushortT* b0 = vtx + (size_t)c * 128;
        acc_t = fmaf(al, b2f(b0[lane]), acc_t);
        acc_x = fmaf(be, b2f(b0[lane + 64]), acc_x);
      }
    }
    out_t[nb + lane] = acc_t;
    out_x[nb + lane] = acc_x;
  }
}

// ---------------------------------------------------------------------------
extern "C" void kernel_launch(void* const* d_in, const int* in_sizes, int n_in,
                              void* d_out, int out_size, void* d_ws, size_t ws_size,
                              hipStream_t stream) {
  const float* x_src = (const float*)d_in[0];
  const float* x_tgt = (const float*)d_in[1];
  const float* t_src = (const float*)d_in[2];
  const float* t_tgt = (const float*)d_in[3];
  const void* edge_index = d_in[4];
  const float* W_x = (const float*)d_in[5];
  const float* W_t = (const float*)d_in[6];
  const float* Ka_W = (const float*)d_in[7];
  const float* Ka_b = (const float*)d_in[8];
  const float* Qa_W = (const float*)d_in[9];
  const float* Qa_b = (const float*)d_in[10];
  const float* Kb_W = (const float*)d_in[11];
  const float* Kb_b = (const float*)d_in[12];
  const float* Qb_W = (const float*)d_in[13];
  const float* Qb_b = (const float*)d_in[14];

  const int N = in_sizes[0] / D;
  const int E = in_sizes[4] / 2;

  char* ws = (char*)d_ws;
  size_t ofs = 0;
  auto carve = [&](size_t bytes) {
    size_t p = ofs;
    ofs += (bytes + 255) & ~(size_t)255;
    return p;
  };
  float* qab = (float*)(ws + carve((size_t)N * 128 * 4));
  ushortT* kab = (ushortT*)(ws + carve((size_t)N * 128 * 2));
  ushortT* vtx = (ushortT*)(ws + carve((size_t)N * 128 * 2));
  int* offs = (int*)(ws + carve(((size_t)N + 1) * 4));
  int* deg = (int*)(ws + carve((size_t)N * 4));
  int* rank = (int*)(ws + carve((size_t)E * 4));
  int* ecol = (int*)(ws + carve((size_t)E * 4));
  (void)ws_size;

  float* out_x = (float*)d_out;
  float* out_t = out_x + (size_t)N * D;

  const int scatBlocks = ((E + 3) / 4 + 255) / 256;
  const int bpj = (N + 127) / 128;

  hipMemsetAsync(deg, 0, (size_t)N * 4, stream);
  edge_rank<<<scatBlocks, 256, 0, stream>>>(edge_index, deg, rank, E, (ull)N);
  scan_offs<<<1, 1024, 0, stream>>>(deg, offs, N, E);
  scat_proj<<<scatBlocks + 4 * bpj, 256, 0, stream>>>(
      edge_index, offs, rank, ecol, E,
      t_tgt, x_tgt, t_src, x_src,
      Qa_W, Qa_b, Qb_W, Qb_b,
      Ka_W, Ka_b, W_t,
      Kb_W, Kb_b, W_x,
      qab, kab, vtx, N, bpj, scatBlocks);
  node_attn<<<(N + 3) / 4, 256, 0, stream>>>(qab, kab, vtx, offs, ecol,
                                             out_x, out_t, N);
}

// Round 8
// 247.020 us; speedup vs baseline: 2.5593x; 1.3499x over previous
//
#include <hip/hip_runtime.h>
#include <math.h>

// ---------------------------------------------------------------------------
// CrossAttentionGNNConv: N=50000, E=800000, D=64
// 6 dispatches: memset(deg) -> edge_rank -> scan_part -> scan_add ->
//               scat_proj (scatter || MFMA projections) -> node_attn(flash)
// Layouts: qab[n][128] f32 = [q_a|q_b]; kab[n][128] bf16 = [k_a|k_b];
//          vtx[n][128] bf16 = [v_t|v_x]
// R6 lesson: device-scope grid barriers cost ~100x model (cross-XCD); use
// kernel boundaries. R7 lesson: LDS-heavy attn kills occupancy; single-block
// scan serializes. node_attn is now LDS-free single-pass online softmax.
// ---------------------------------------------------------------------------

#define D 64
#define NINF -3.0e38f
#define AROW 72
typedef unsigned short ushortT;
typedef unsigned long long ull;
typedef __attribute__((ext_vector_type(8))) short bf16x8;
typedef __attribute__((ext_vector_type(4))) float f32x4;

__device__ __forceinline__ float b2f_lo(unsigned u) {
  return __uint_as_float(u << 16);
}
__device__ __forceinline__ float b2f_hi(unsigned u) {
  return __uint_as_float(u & 0xffff0000u);
}
__device__ __forceinline__ ushortT f2b(float f) {
  unsigned u = __float_as_uint(f);
  u += 0x7fffu + ((u >> 16) & 1u);
  return (ushortT)(u >> 16);
}

__device__ __forceinline__ bool wave_is64(const ull* __restrict__ ei, ull nNodes) {
  ull v = ei[threadIdx.x & 63];
  return __ballot(v >= nNodes) == 0ull;
}

// --- CSR pass 1: histogram rows, record per-edge rank ----------------------
__global__ void edge_rank(const void* __restrict__ ei, int* __restrict__ deg,
                          int* __restrict__ rank, int E, ull nNodes) {
  const bool is64 = wave_is64((const ull*)ei, nNodes);
  int base = (blockIdx.x * blockDim.x + threadIdx.x) << 2;
  if (base >= E) return;
  int m = E - base; if (m > 4) m = 4;
  if (is64) {
    const long long* p = (const long long*)ei;
    for (int j = 0; j < m; ++j) {
      int r = (int)p[base + j];
      rank[base + j] = atomicAdd(&deg[r], 1);
    }
  } else {
    const int* p = (const int*)ei;
    for (int j = 0; j < m; ++j) {
      int r = p[base + j];
      rank[base + j] = atomicAdd(&deg[r], 1);
    }
  }
}

// --- CSR pass 2a: per-block local exclusive scan + block sums --------------
__global__ void scan_part(const int* __restrict__ deg, int* __restrict__ offs,
                          int* __restrict__ bsum, int N) {
  __shared__ int sI[256];
  const int t = threadIdx.x;
  const int i = blockIdx.x * 256 + t;
  int d = (i < N) ? deg[i] : 0;
  sI[t] = d;
  __syncthreads();
  for (int off = 1; off < 256; off <<= 1) {
    int add = (t >= off) ? sI[t - off] : 0;
    __syncthreads();
    sI[t] += add;
    __syncthreads();
  }
  if (i < N) offs[i] = sI[t] - d;  // local exclusive
  if (t == 255) bsum[blockIdx.x] = sI[255];
}

// --- CSR pass 2b: each block scans all block sums, adds its base -----------
__global__ void scan_add(int* __restrict__ offs, const int* __restrict__ bsum,
                         int N, int E, int nB) {
  __shared__ int sI[256];
  const int t = threadIdx.x;
  int v = (t < nB) ? bsum[t] : 0;
  sI[t] = v;
  __syncthreads();
  for (int off = 1; off < 256; off <<= 1) {
    int add = (t >= off) ? sI[t - off] : 0;
    __syncthreads();
    sI[t] += add;
    __syncthreads();
  }
  const int base = sI[blockIdx.x] - bsum[blockIdx.x];  // exclusive prefix
  const int i = blockIdx.x * 256 + t;
  if (i < N) offs[i] += base;
  if (blockIdx.x == 0 && t == 0) offs[N] = E;
}

// --- fused: atomic-free scatter (blocks < scatBlocks) || MFMA proj ---------
__global__ __launch_bounds__(256) void scat_proj(
    const void* __restrict__ ei, const int* __restrict__ offs,
    const int* __restrict__ rank, int* __restrict__ ecol, int E,
    const float* __restrict__ t_tgt, const float* __restrict__ x_tgt,
    const float* __restrict__ t_src, const float* __restrict__ x_src,
    const float* __restrict__ QaW, const float* __restrict__ Qab_,
    const float* __restrict__ QbW, const float* __restrict__ Qbb,
    const float* __restrict__ KaW, const float* __restrict__ Kab_,
    const float* __restrict__ Wt,
    const float* __restrict__ KbW, const float* __restrict__ Kbb,
    const float* __restrict__ Wx,
    float* __restrict__ qab, ushortT* __restrict__ kab, ushortT* __restrict__ vtx,
    int N, int bpj, int scatBlocks) {
  __shared__ ushortT As[128 * AROW];
  __shared__ ushortT W0s[64 * AROW];
  __shared__ ushortT W1s[64 * AROW];
  const int tid = threadIdx.x;

  if (blockIdx.x < scatBlocks) {
    const bool is64 = wave_is64((const ull*)ei, (ull)N);
    int base = (blockIdx.x * 256 + tid) << 2;
    if (base >= E) return;
    int m = E - base; if (m > 4) m = 4;
    if (is64) {
      const long long* p = (const long long*)ei;
      for (int j = 0; j < m; ++j) {
        int r = (int)p[base + j];
        int c = (int)p[(long long)E + base + j];
        ecol[offs[r] + rank[base + j]] = c;
      }
    } else {
      const int* p = (const int*)ei;
      for (int j = 0; j < m; ++j) {
        int r = p[base + j];
        int c = p[E + base + j];
        ecol[offs[r] + rank[base + j]] = c;
      }
    }
    return;
  }

  // ---------------- projection tile ----------------
  const int tile = blockIdx.x - scatBlocks;
  const int job = tile / bpj;
  const int jb = tile % bpj;
  const float *X, *W0, *B0, *W1 = nullptr;
  switch (job) {
    case 0: X = t_tgt; W0 = QaW; B0 = Qab_; break;
    case 1: X = x_tgt; W0 = QbW; B0 = Qbb; break;
    case 2: X = t_src; W0 = KaW; B0 = Kab_; W1 = Wt; break;
    default: X = x_src; W0 = KbW; B0 = Kbb; W1 = Wx; break;
  }
  const bool dual = (job >= 2);
  const int half = (job & 1) ? 64 : 0;
  const int base = jb * 128;

#pragma unroll
  for (int r = 0; r < 8; ++r) {
    int idx = tid + 256 * r;
    int row = idx >> 4, k4 = idx & 15;
    int gnode = base + row;
    float4 v = make_float4(0.f, 0.f, 0.f, 0.f);
    if (gnode < N) v = *(const float4*)(X + (size_t)gnode * D + k4 * 4);
    ushort4 h;
    h.x = f2b(v.x); h.y = f2b(v.y); h.z = f2b(v.z); h.w = f2b(v.w);
    *(ushort4*)&As[row * AROW + k4 * 4] = h;
  }
#pragma unroll
  for (int r = 0; r < 4; ++r) {
    int idx = tid + 256 * r;
    int row = idx >> 4, k4 = idx & 15;
    float4 v = *(const float4*)(W0 + row * D + k4 * 4);
    ushort4 h;
    h.x = f2b(v.x); h.y = f2b(v.y); h.z = f2b(v.z); h.w = f2b(v.w);
    *(ushort4*)&W0s[row * AROW + k4 * 4] = h;
  }
  if (dual) {
#pragma unroll
    for (int r = 0; r < 4; ++r) {
      int idx = tid + 256 * r;
      int row = idx >> 4, k4 = idx & 15;
      float4 v = *(const float4*)(W1 + row * D + k4 * 4);
      ushort4 h;
      h.x = f2b(v.x); h.y = f2b(v.y); h.z = f2b(v.z); h.w = f2b(v.w);
      *(ushort4*)&W1s[row * AROW + k4 * 4] = h;
    }
  }
  __syncthreads();

  const int lane = tid & 63;
  const int wid = tid >> 6;
  const int m16 = lane & 15;
  const int quad = lane >> 4;

  f32x4 acc0[2][4], acc1[2][4];
#pragma unroll
  for (int mt = 0; mt < 2; ++mt)
#pragma unroll
    for (int nt = 0; nt < 4; ++nt) {
      acc0[mt][nt] = (f32x4){0.f, 0.f, 0.f, 0.f};
      acc1[mt][nt] = (f32x4){0.f, 0.f, 0.f, 0.f};
    }
#pragma unroll
  for (int ko = 0; ko < 2; ++ko) {
    const int koff = ko * 32 + quad * 8;
    bf16x8 a[2];
#pragma unroll
    for (int mt = 0; mt < 2; ++mt)
      a[mt] = *(const bf16x8*)&As[(wid * 32 + mt * 16 + m16) * AROW + koff];
#pragma unroll
    for (int nt = 0; nt < 4; ++nt) {
      bf16x8 b = *(const bf16x8*)&W0s[(nt * 16 + m16) * AROW + koff];
#pragma unroll
      for (int mt = 0; mt < 2; ++mt)
        acc0[mt][nt] = __builtin_amdgcn_mfma_f32_16x16x32_bf16(
            a[mt], b, acc0[mt][nt], 0, 0, 0);
    }
    if (dual) {
#pragma unroll
      for (int nt = 0; nt < 4; ++nt) {
        bf16x8 b = *(const bf16x8*)&W1s[(nt * 16 + m16) * AROW + koff];
#pragma unroll
        for (int mt = 0; mt < 2; ++mt)
          acc1[mt][nt] = __builtin_amdgcn_mfma_f32_16x16x32_bf16(
              a[mt], b, acc1[mt][nt], 0, 0, 0);
      }
    }
  }

  float bias[4];
#pragma unroll
  for (int nt = 0; nt < 4; ++nt) bias[nt] = B0[nt * 16 + m16];
#pragma unroll
  for (int mt = 0; mt < 2; ++mt) {
#pragma unroll
    for (int reg = 0; reg < 4; ++reg) {
      int node = base + wid * 32 + mt * 16 + quad * 4 + reg;
      if (node < N) {
        if (!dual) {
          float* dst = qab + (size_t)node * 128 + half;
#pragma unroll
          for (int nt = 0; nt < 4; ++nt)
            dst[nt * 16 + m16] = acc0[mt][nt][reg] + bias[nt];
        } else {
          ushortT* dk = kab + (size_t)node * 128 + half;
          ushortT* dv = vtx + (size_t)node * 128 + half;
#pragma unroll
          for (int nt = 0; nt < 4; ++nt) {
            dk[nt * 16 + m16] = f2b(acc0[mt][nt][reg] + bias[nt]);
            dv[nt * 16 + m16] = f2b(acc1[mt][nt][reg]);
          }
        }
      }
    }
  }
}

// --- node attention: single-pass flash-style online softmax, zero LDS ------
// One wave per node. 4 subgroups x 16 lanes; each subgroup handles one edge
// per pass. Lane (sub, sl) owns output positions sl*8..sl*8+7 of [t|x]:
// sl<8 -> t-half (alpha chain), sl>=8 -> x-half (beta chain). Per lane:
// online (m, d, acc[8]); K-row and V-row gathers issued together.
__global__ __launch_bounds__(256) void node_attn(
    const float* __restrict__ qab, const ushortT* __restrict__ kab,
    const ushortT* __restrict__ vtx,
    const int* __restrict__ offs, const int* __restrict__ ecol,
    float* __restrict__ out_x, float* __restrict__ out_t, int nNodes) {
  const int lane = threadIdx.x & 63;
  const int sub = lane >> 4;   // subgroup = edge slot within pass
  const int sl = lane & 15;
  const int gw = (blockIdx.x * blockDim.x + threadIdx.x) >> 6;
  const int nw = (gridDim.x * blockDim.x) >> 6;
  const float scale = 0.125f;

  for (int n = gw; n < nNodes; n += nw) {
    const int s = offs[n], e = offs[n + 1], deg = e - s;
    const size_t nb = (size_t)n * D;
    if (deg == 0) {
#pragma unroll
      for (int j = 0; j < 2; ++j) {
        // all lanes write zeros (64 lanes cover both halves)
      }
      out_t[nb + lane] = 0.f;
      out_x[nb + lane] = 0.f;
      continue;
    }
    const float4 q0 = *(const float4*)(qab + (size_t)n * 128 + sl * 8);
    const float4 q1 = *(const float4*)(qab + (size_t)n * 128 + sl * 8 + 4);

    float m = NINF, d = 0.f;
    float acc[8];
#pragma unroll
    for (int j = 0; j < 8; ++j) acc[j] = 0.f;

    for (int i = 0; i < deg; i += 8) {
      const int i0 = i + sub;
      const int i1 = i + 4 + sub;
      const bool a0 = i0 < deg, a1 = i1 < deg;
      const int c0 = ecol[s + (a0 ? i0 : 0)];
      const int c1 = ecol[s + (a1 ? i1 : 0)];
      // issue all four gathers up front
      const uint4 k0 = *(const uint4*)(kab + (size_t)c0 * 128 + sl * 8);
      const uint4 v0 = *(const uint4*)(vtx + (size_t)c0 * 128 + sl * 8);
      const uint4 k1 = *(const uint4*)(kab + (size_t)c1 * 128 + sl * 8);
      const uint4 v1 = *(const uint4*)(vtx + (size_t)c1 * 128 + sl * 8);

      // --- edge 0 ---
      {
        float t = q0.x * b2f_lo(k0.x);
        t = fmaf(q0.y, b2f_hi(k0.x), t);
        t = fmaf(q0.z, b2f_lo(k0.y), t);
        t = fmaf(q0.w, b2f_hi(k0.y), t);
        t = fmaf(q1.x, b2f_lo(k0.z), t);
        t = fmaf(q1.y, b2f_hi(k0.z), t);
        t = fmaf(q1.z, b2f_lo(k0.w), t);
        t = fmaf(q1.w, b2f_hi(k0.w), t);
#pragma unroll
        for (int off = 1; off < 8; off <<= 1) t += __shfl_xor(t, off);
        const float sc = a0 ? t * scale : NINF;
        const float mN = fmaxf(m, sc);
        const float f = __expf(m - mN);
        const float w = a0 ? __expf(sc - mN) : 0.f;
        d = d * f + w;
        acc[0] = fmaf(acc[0], f, w * b2f_lo(v0.x));
        acc[1] = fmaf(acc[1], f, w * b2f_hi(v0.x));
        acc[2] = fmaf(acc[2], f, w * b2f_lo(v0.y));
        acc[3] = fmaf(acc[3], f, w * b2f_hi(v0.y));
        acc[4] = fmaf(acc[4], f, w * b2f_lo(v0.z));
        acc[5] = fmaf(acc[5], f, w * b2f_hi(v0.z));
        acc[6] = fmaf(acc[6], f, w * b2f_lo(v0.w));
        acc[7] = fmaf(acc[7], f, w * b2f_hi(v0.w));
        m = mN;
      }
      // --- edge 1 ---
      {
        float t = q0.x * b2f_lo(k1.x);
        t = fmaf(q0.y, b2f_hi(k1.x), t);
        t = fmaf(q0.z, b2f_lo(k1.y), t);
        t = fmaf(q0.w, b2f_hi(k1.y), t);
        t = fmaf(q1.x, b2f_lo(k1.z), t);
        t = fmaf(q1.y, b2f_hi(k1.z), t);
        t = fmaf(q1.z, b2f_lo(k1.w), t);
        t = fmaf(q1.w, b2f_hi(k1.w), t);
#pragma unroll
        for (int off = 1; off < 8; off <<= 1) t += __shfl_xor(t, off);
        const float sc = a1 ? t * scale : NINF;
        const float mN = fmaxf(m, sc);
        const float f = __expf(m - mN);
        const float w = a1 ? __expf(sc - mN) : 0.f;
        d = d * f + w;
        acc[0] = fmaf(acc[0], f, w * b2f_lo(v1.x));
        acc[1] = fmaf(acc[1], f, w * b2f_hi(v1.x));
        acc[2] = fmaf(acc[2], f, w * b2f_lo(v1.y));
        acc[3] = fmaf(acc[3], f, w * b2f_hi(v1.y));
        acc[4] = fmaf(acc[4], f, w * b2f_lo(v1.z));
        acc[5] = fmaf(acc[5], f, w * b2f_hi(v1.z));
        acc[6] = fmaf(acc[6], f, w * b2f_lo(v1.w));
        acc[7] = fmaf(acc[7], f, w * b2f_hi(v1.w));
        m = mN;
      }
    }

    // cross-subgroup combine (lanes differing in bits 4,5)
    float mg = m;
#pragma unroll
    for (int off = 16; off < 64; off <<= 1) mg = fmaxf(mg, __shfl_xor(mg, off));
    const float fg = __expf(m - mg);  // 0 for empty subgroups (m = NINF)
    d *= fg;
#pragma unroll
    for (int j = 0; j < 8; ++j) acc[j] *= fg;
#pragma unroll
    for (int off = 16; off < 64; off <<= 1) {
      d += __shfl_xor(d, off);
#pragma unroll
      for (int j = 0; j < 8; ++j) acc[j] += __shfl_xor(acc[j], off);
    }
    const float inv = 1.0f / d;
    if (sub == 0) {
      float4 o0, o1;
      o0.x = acc[0] * inv; o0.y = acc[1] * inv;
      o0.z = acc[2] * inv; o0.w = acc[3] * inv;
      o1.x = acc[4] * inv; o1.y = acc[5] * inv;
      o1.z = acc[6] * inv; o1.w = acc[7] * inv;
      float* dst = (sl < 8) ? (out_t + nb + sl * 8) : (out_x + nb + (sl - 8) * 8);
      *(float4*)dst = o0;
      *(float4*)(dst + 4) = o1;
    }
  }
}

// ---------------------------------------------------------------------------
extern "C" void kernel_launch(void* const* d_in, const int* in_sizes, int n_in,
                              void* d_out, int out_size, void* d_ws, size_t ws_size,
                              hipStream_t stream) {
  const float* x_src = (const float*)d_in[0];
  const float* x_tgt = (const float*)d_in[1];
  const float* t_src = (const float*)d_in[2];
  const float* t_tgt = (const float*)d_in[3];
  const void* edge_index = d_in[4];
  const float* W_x = (const float*)d_in[5];
  const float* W_t = (const float*)d_in[6];
  const float* Ka_W = (const float*)d_in[7];
  const float* Ka_b = (const float*)d_in[8];
  const float* Qa_W = (const float*)d_in[9];
  const float* Qa_b = (const float*)d_in[10];
  const float* Kb_W = (const float*)d_in[11];
  const float* Kb_b = (const float*)d_in[12];
  const float* Qb_W = (const float*)d_in[13];
  const float* Qb_b = (const float*)d_in[14];

  const int N = in_sizes[0] / D;
  const int E = in_sizes[4] / 2;
  const int nB = (N + 255) / 256;  // <= 256

  char* ws = (char*)d_ws;
  size_t ofs = 0;
  auto carve = [&](size_t bytes) {
    size_t p = ofs;
    ofs += (bytes + 255) & ~(size_t)255;
    return p;
  };
  float* qab = (float*)(ws + carve((size_t)N * 128 * 4));
  ushortT* kab = (ushortT*)(ws + carve((size_t)N * 128 * 2));
  ushortT* vtx = (ushortT*)(ws + carve((size_t)N * 128 * 2));
  int* offs = (int*)(ws + carve(((size_t)N + 1) * 4));
  int* deg = (int*)(ws + carve((size_t)N * 4));
  int* bsum = (int*)(ws + carve((size_t)nB * 4));
  int* rank = (int*)(ws + carve((size_t)E * 4));
  int* ecol = (int*)(ws + carve((size_t)E * 4));
  (void)ws_size;

  float* out_x = (float*)d_out;
  float* out_t = out_x + (size_t)N * D;

  const int scatBlocks = ((E + 3) / 4 + 255) / 256;
  const int bpj = (N + 127) / 128;

  hipMemsetAsync(deg, 0, (size_t)N * 4, stream);
  edge_rank<<<scatBlocks, 256, 0, stream>>>(edge_index, deg, rank, E, (ull)N);
  scan_part<<<nB, 256, 0, stream>>>(deg, offs, bsum, N);
  scan_add<<<nB, 256, 0, stream>>>(offs, bsum, N, E, nB);
  scat_proj<<<scatBlocks + 4 * bpj, 256, 0, stream>>>(
      edge_index, offs, rank, ecol, E,
      t_tgt, x_tgt, t_src, x_src,
      Qa_W, Qa_b, Qb_W, Qb_b,
      Ka_W, Ka_b, W_t,
      Kb_W, Kb_b, W_x,
      qab, kab, vtx, N, bpj, scatBlocks);
  node_attn<<<(N + 3) / 4, 256, 0, stream>>>(qab, kab, vtx, offs, ecol,
                                             out_x, out_t, N);
}